// Round 11
// baseline (386.975 us; speedup 1.0000x reference)
//
#include <hip/hip_runtime.h>
#include <hip/hip_bf16.h>
#include <hip/hip_cooperative_groups.h>

namespace cg = cooperative_groups;

#define B_ 2
#define S_ 2048
#define D_ 1024
#define N_ 16
#define R_ 64
#define NC 64          // number of scan chunks
#define CL 32          // chunk length  (NC*CL == S_)
#define BS_ (B_*S_)

typedef __attribute__((ext_vector_type(4))) float f32x4;
typedef __attribute__((ext_vector_type(8))) short bf16x8;
typedef __attribute__((ext_vector_type(8))) unsigned short u16x8;

__device__ __forceinline__ unsigned short f2b(float v) {
  unsigned u = __builtin_bit_cast(unsigned, v);
  unsigned r = ((u >> 16) & 1u) + 0x7FFFu;
  return (unsigned short)((u + r) >> 16);
}

__device__ __forceinline__ void gload_lds16(const void* g, void* l) {
  __builtin_amdgcn_global_load_lds(
      (const __attribute__((address_space(1))) unsigned int*)g,
      (__attribute__((address_space(3))) unsigned int*)l, 16, 0, 0);
}

// ---------------- casts + direct fp32 W_eff GEMM, one kernel ----------------
// blocks 0..4095   : x     -> xb         (bf16 cast)
// blocks 4096..4111: W_B   -> WBC[0:16)  rows
// blocks 4112..4127: W_C   -> WBC[16:32) rows
// blocks 4128..5151: W_out -> wob
// blocks 5152..6175: weff[d][:] = W_dt[d][:] . W_dtw  (fp32 accum, bf16 out)
__global__ __launch_bounds__(256) void k_castweff(
    const float* __restrict__ x, const float* __restrict__ W_B,
    const float* __restrict__ W_C, const float* __restrict__ W_out,
    const float* __restrict__ W_dt, const float* __restrict__ W_dtw,
    unsigned short* __restrict__ xb, unsigned short* __restrict__ WBC,
    unsigned short* __restrict__ wob, unsigned short* __restrict__ weff) {
  const int blk = blockIdx.x, tid = threadIdx.x;
  if (blk < 5152) {
    const float* s; unsigned short* d; int base;
    if (blk < 4096)      { s = x;     d = xb;          base = 0; }
    else if (blk < 4112) { s = W_B;   d = WBC;         base = 4096; }
    else if (blk < 4128) { s = W_C;   d = WBC + 16384; base = 4112; }
    else                 { s = W_out; d = wob;         base = 4128; }
    int j = (blk - base) * 1024 + tid * 4;
    float4 v = *(const float4*)&s[j];
    ushort4 o;
    o.x = f2b(v.x); o.y = f2b(v.y); o.z = f2b(v.z); o.w = f2b(v.w);
    *(ushort4*)&d[j] = o;
  } else {
    const int dd = blk - 5152;                 // output row d
    const float* wdt = W_dt + (size_t)dd * R_;
    const int e4 = tid * 4;
    float a0 = 0.f, a1 = 0.f, a2 = 0.f, a3 = 0.f;
    #pragma unroll 8
    for (int r = 0; r < R_; ++r) {
      float w = wdt[r];                        // block-uniform -> scalar load
      float4 ww = *(const float4*)&W_dtw[(size_t)r * D_ + e4];
      a0 += w * ww.x; a1 += w * ww.y; a2 += w * ww.z; a3 += w * ww.w;
    }
    ushort4 o;
    o.x = f2b(a0); o.y = f2b(a1); o.z = f2b(a2); o.w = f2b(a3);
    *(ushort4*)&weff[(size_t)dd * D_ + e4] = o;
  }
}

// ---------------- shared staging helper: 64x64 u16 tile ----------------
__device__ __forceinline__ void stage64x64(const unsigned short* __restrict__ g,
                                           size_t row0, int k0,
                                           unsigned short* lds, int tid) {
  const int r = tid >> 3, s = tid & 7;
  #pragma unroll
  for (int i = 0; i < 2; ++i) {
    const int row = i * 32 + r;
    const int gs = s ^ (row & 7);
    gload_lds16(g + ((row0 + row) << 10) + k0 + (gs << 3), lds + row * 64 + s * 8);
  }
}

// ---------------- fused delta + B/C projection GEMM, BM=64 BN=64 ----------------
// grid (64, 17): by<16 -> delta[:, by*64..+63] = softplus(xb . weff^T + b_dt)
//                by==16 -> Bm,Cm = xb . WBC^T (32 cols)
// 4 blocks/CU co-resident (R9/R10 lesson). All acc indices literal (rule #20).
__global__ __launch_bounds__(256, 4) void k_deltaBC(
    const unsigned short* __restrict__ xb, const unsigned short* __restrict__ weff,
    const unsigned short* __restrict__ WBC, const float* __restrict__ b_dt,
    float* __restrict__ delta, float* __restrict__ Bm, float* __restrict__ Cm) {
  __shared__ __align__(16) unsigned short As[2][64 * 64];  // 2x8KB
  __shared__ __align__(16) unsigned short Bs[2][64 * 64];  // 2x8KB
  const int tid = threadIdx.x;
  const int lane = tid & 63, wid = tid >> 6;
  const size_t row0 = (size_t)blockIdx.x * 64;
  const int by = blockIdx.y;
  const bool bc = (by == 16);
  f32x4 acc[4] = {};

  auto stageB = [&](int buf, int k0) {
    if (!bc) {
      stage64x64(weff, (size_t)by * 64, k0, Bs[buf], tid);
    } else {
      const int row = tid >> 3, s = tid & 7;       // 32 rows, 1 load/thread
      const int gs = s ^ (row & 7);
      gload_lds16(WBC + (size_t)row * D_ + k0 + (gs << 3), Bs[buf] + row * 64 + s * 8);
    }
  };

  stage64x64(xb, row0, 0, As[0], tid);
  stageB(0, 0);
  __syncthreads();

  int cur = 0;
  const int r = lane & 15, kg = lane >> 4;
  for (int t = 0; t < 16; ++t) {
    if (t + 1 < 16) {
      stage64x64(xb, row0, (t + 1) * 64, As[cur ^ 1], tid);
      stageB(cur ^ 1, (t + 1) * 64);
    }
    if (!bc) {
      #pragma unroll
      for (int ks = 0; ks < 2; ++ks) {
        const int arow = wid * 16 + r;
        bf16x8 a = *(const bf16x8*)&As[cur][arow * 64 + (((ks << 2) | kg) ^ (arow & 7)) * 8];
        bf16x8 b0, b1, b2, b3;
        b0 = *(const bf16x8*)&Bs[cur][(0 * 16 + r) * 64 + (((ks << 2) | kg) ^ ((0 * 16 + r) & 7)) * 8];
        b1 = *(const bf16x8*)&Bs[cur][(1 * 16 + r) * 64 + (((ks << 2) | kg) ^ ((1 * 16 + r) & 7)) * 8];
        b2 = *(const bf16x8*)&Bs[cur][(2 * 16 + r) * 64 + (((ks << 2) | kg) ^ ((2 * 16 + r) & 7)) * 8];
        b3 = *(const bf16x8*)&Bs[cur][(3 * 16 + r) * 64 + (((ks << 2) | kg) ^ ((3 * 16 + r) & 7)) * 8];
        acc[0] = __builtin_amdgcn_mfma_f32_16x16x32_bf16(a, b0, acc[0], 0, 0, 0);
        acc[1] = __builtin_amdgcn_mfma_f32_16x16x32_bf16(a, b1, acc[1], 0, 0, 0);
        acc[2] = __builtin_amdgcn_mfma_f32_16x16x32_bf16(a, b2, acc[2], 0, 0, 0);
        acc[3] = __builtin_amdgcn_mfma_f32_16x16x32_bf16(a, b3, acc[3], 0, 0, 0);
      }
    } else {
      #pragma unroll
      for (int ks = 0; ks < 2; ++ks) {
        const int arow = wid * 16 + r;
        bf16x8 a = *(const bf16x8*)&As[cur][arow * 64 + (((ks << 2) | kg) ^ (arow & 7)) * 8];
        bf16x8 b0, b1;
        b0 = *(const bf16x8*)&Bs[cur][(0 * 16 + r) * 64 + (((ks << 2) | kg) ^ ((0 * 16 + r) & 7)) * 8];
        b1 = *(const bf16x8*)&Bs[cur][(1 * 16 + r) * 64 + (((ks << 2) | kg) ^ ((1 * 16 + r) & 7)) * 8];
        acc[0] = __builtin_amdgcn_mfma_f32_16x16x32_bf16(a, b0, acc[0], 0, 0, 0);
        acc[1] = __builtin_amdgcn_mfma_f32_16x16x32_bf16(a, b1, acc[1], 0, 0, 0);
      }
    }
    __syncthreads();
    cur ^= 1;
  }

  const int cr = lane >> 4, cc = lane & 15;
  if (!bc) {
    #pragma unroll
    for (int n = 0; n < 4; ++n) {
      const int d = by * 64 + n * 16 + cc;
      const float bd = b_dt[d];
      #pragma unroll
      for (int j = 0; j < 4; ++j) {
        size_t trow = row0 + wid * 16 + cr * 4 + j;
        float v = acc[n][j] + bd;
        float sp = fmaxf(v, 0.f) + log1pf(__expf(-fabsf(v)));
        delta[trow * D_ + d] = sp;
      }
    }
  } else {
    #pragma unroll
    for (int n = 0; n < 2; ++n) {
      const int col = n * 16 + cc;
      #pragma unroll
      for (int j = 0; j < 4; ++j) {
        size_t trow = row0 + wid * 16 + cr * 4 + j;
        float v = acc[n][j];
        if (col < 16) Bm[trow * N_ + col] = v;
        else          Cm[trow * N_ + col - 16] = v;
      }
    }
  }
}

// ---------------- cooperative fused scan: phase1 local / phase2 chunk / phase3 corr ----
// grid = B*(NC/2)*16 = 1024 blocks, 256 thr. LDS 32KB -> 5 blocks/CU capacity,
// need 4 -> co-residency guaranteed; launch_bounds(256,4) caps VGPR at 128.
// sx doubles as the y buffer after phase1 (each sx[s][dl] is read/written only
// by its own wave's 4-lane quad, in program order -- no cross-wave hazard).
__global__ __launch_bounds__(256, 4) void k_scanall(
    const float* __restrict__ x, const float* __restrict__ delta,
    const float* __restrict__ Bm, const float* __restrict__ Cm,
    const float* __restrict__ A_log, const float* __restrict__ Dp,
    float* __restrict__ sdsum, float* __restrict__ hend,
    float* __restrict__ hstart, float* __restrict__ ypre) {
  __shared__ __align__(16) float sd[2][CL][64];   // 16KB
  __shared__ __align__(16) float sx[2][CL][64];   // 16KB, becomes y after phase1
  const int tid = threadIdx.x;
  const int slab = blockIdx.x & 15;
  const int cp   = (blockIdx.x >> 4) & 31;
  const int b    = blockIdx.x >> 9;
  const int d0 = slab * 64;
  const int c0 = cp * 2;

  {   // stage both chunks (async, linear dest = base + lane*16)
    int s = tid >> 4, jf = (tid & 15) * 4;
    #pragma unroll
    for (int cc = 0; cc < 2; ++cc) {
      size_t tokb = (size_t)(b * S_ + (c0 + cc) * CL);
      size_t g = (tokb + s) * D_ + d0 + jf;
      gload_lds16(&delta[g],                   &sd[cc][s][jf]);
      gload_lds16(&delta[g + (size_t)16 * D_], &sd[cc][s + 16][jf]);
      gload_lds16(&x[g],                       &sx[cc][s][jf]);
      gload_lds16(&x[g + (size_t)16 * D_],     &sx[cc][s + 16][jf]);
    }
  }
  const int nq = tid & 3, dl = tid >> 2;
  const int d = d0 + dl;
  float4 av = *(const float4*)&A_log[(size_t)d * N_ + nq * 4];
  float Ad0 = -__expf(av.x), Ad1 = -__expf(av.y);
  float Ad2 = -__expf(av.z), Ad3 = -__expf(av.w);
  const float Dpd = Dp[d];
  __syncthreads();

  // ---- phase 1: local scans (h0 = 0); y_loc + Dp*x written over sx ----
  #pragma unroll
  for (int cc = 0; cc < 2; ++cc) {
    const int c = c0 + cc;
    size_t bcb = (size_t)(b * S_ + c * CL) * N_ + nq * 4;
    float sds = 0.f, h0 = 0.f, h1 = 0.f, h2 = 0.f, h3 = 0.f;
    #pragma unroll 8
    for (int s = 0; s < CL; ++s) {
      float dlt = sd[cc][s][dl];
      float xv  = sx[cc][s][dl];
      float dbx = dlt * xv;
      sds += dlt;
      float4 Bv = *(const float4*)&Bm[bcb + (size_t)s * N_];
      float4 Cv = *(const float4*)&Cm[bcb + (size_t)s * N_];
      float da0 = __expf(dlt * Ad0), da1 = __expf(dlt * Ad1);
      float da2 = __expf(dlt * Ad2), da3 = __expf(dlt * Ad3);
      h0 = da0 * h0 + dbx * Bv.x;
      h1 = da1 * h1 + dbx * Bv.y;
      h2 = da2 * h2 + dbx * Bv.z;
      h3 = da3 * h3 + dbx * Bv.w;
      float y = h0 * Cv.x + h1 * Cv.y + h2 * Cv.z + h3 * Cv.w;
      y += __shfl_xor(y, 1);
      y += __shfl_xor(y, 2);
      if (nq == 0) sx[cc][s][dl] = y + Dpd * xv;   // after last read of sx[s][dl]
    }
    size_t o = (((size_t)(b * NC + c)) * D_ + d) * N_ + nq * 4;
    *(float4*)&hend[o] = make_float4(h0, h1, h2, h3);
    if (nq == 0) sdsum[(size_t)(b * NC + c) * D_ + d] = sds;
  }

  cg::this_grid().sync();

  // ---- phase 2: chunk-summary scan (R9's verified hierarchical scheme) ----
  {
    const int o2  = tid & 7;
    const int n2  = (tid >> 3) & 15;
    const int dl2 = tid >> 7;
    const int d22 = blockIdx.x & 511;
    const int b2  = blockIdx.x >> 9;
    const int dd  = d22 * 2 + dl2;
    const float Ad = -__expf(A_log[(size_t)dd * N_ + n2]);
    float ap8[8], he8[8];
    float A_loc = 1.f, H_loc = 0.f;
    #pragma unroll
    for (int k = 0; k < 8; ++k) {
      const int c = o2 * 8 + k;
      float sds = sdsum[(size_t)(b2 * NC + c) * D_ + dd];
      float ap = __expf(Ad * sds);
      float he = hend[((size_t)(b2 * NC + c) * D_ + dd) * N_ + n2];
      ap8[k] = ap; he8[k] = he;
      A_loc *= ap;
      H_loc = ap * H_loc + he;
    }
    float h = 0.f;
    const int gb = (tid & 63) & ~7;
    #pragma unroll
    for (int j = 0; j < 7; ++j) {
      float Aj = __shfl(A_loc, gb | j, 64);
      float Hj = __shfl(H_loc, gb | j, 64);
      if (o2 > j) h = Aj * h + Hj;
    }
    #pragma unroll
    for (int k = 0; k < 8; ++k) {
      const int c = o2 * 8 + k;
      hstart[((size_t)(b2 * NC + c) * D_ + dd) * N_ + n2] = h;
      h = ap8[k] * h + he8[k];
    }
  }

  cg::this_grid().sync();

  // ---- phase 3: correction y += C . (exp(A*cum) * hstart), LDS still resident ----
  #pragma unroll
  for (int cc = 0; cc < 2; ++cc) {
    const int c = c0 + cc;
    size_t bcb = (size_t)(b * S_ + c * CL) * N_ + nq * 4;
    float4 hs = *(const float4*)&hstart[(((size_t)(b * NC + c)) * D_ + d) * N_ + nq * 4];
    float cum = 0.f;
    #pragma unroll 8
    for (int s = 0; s < CL; ++s) {
      cum += sd[cc][s][dl];
      float4 Cv = *(const float4*)&Cm[bcb + (size_t)s * N_];
      float corr = hs.x * Cv.x * __expf(Ad0 * cum)
                 + hs.y * Cv.y * __expf(Ad1 * cum)
                 + hs.z * Cv.z * __expf(Ad2 * cum)
                 + hs.w * Cv.w * __expf(Ad3 * cum);
      corr += __shfl_xor(corr, 1);
      corr += __shfl_xor(corr, 2);
      if (nq == 0) sx[cc][s][dl] += corr;
    }
  }
  __syncthreads();
  {   // bulk coalesced write of both y tiles
    int s = tid >> 3, j = (tid & 7) * 8;
    #pragma unroll
    for (int cc = 0; cc < 2; ++cc) {
      size_t g = ((size_t)(b * S_ + (c0 + cc) * CL) + s) * D_ + d0 + j;
      *(float4*)&ypre[g]     = *(float4*)&sx[cc][s][j];
      *(float4*)&ypre[g + 4] = *(float4*)&sx[cc][s][j + 4];
    }
  }
}

// ---------------- layernorm (residual already fused) -> bf16 y ----------------
__device__ __forceinline__ float block_sum256(float v, float* sm) {
  #pragma unroll
  for (int o = 32; o > 0; o >>= 1) v += __shfl_down(v, o, 64);
  int w = threadIdx.x >> 6;
  __syncthreads();
  if ((threadIdx.x & 63) == 0) sm[w] = v;
  __syncthreads();
  return (sm[0] + sm[1]) + (sm[2] + sm[3]);
}

__global__ __launch_bounds__(256) void k_ln(
    const float* __restrict__ ypre, const float* __restrict__ g,
    const float* __restrict__ bta, unsigned short* __restrict__ ybf) {
  __shared__ float sm[4];
  const int t = blockIdx.x;
  const int tid = threadIdx.x;
  size_t base = (size_t)t * D_ + tid * 4;
  float4 v = *(const float4*)&ypre[base];
  float s1 = block_sum256(v.x + v.y + v.z + v.w, sm);
  float mu = s1 * (1.f / D_);
  float cx = v.x - mu, cy = v.y - mu, cz = v.z - mu, cw = v.w - mu;
  float s2 = block_sum256(cx*cx + cy*cy + cz*cz + cw*cw, sm);
  float rs = rsqrtf(s2 * (1.f / D_) + 1e-5f);
  float4 gg = *(const float4*)&g[tid * 4];
  float4 bb = *(const float4*)&bta[tid * 4];
  ushort4 o;
  o.x = f2b(cx * rs * gg.x + bb.x);
  o.y = f2b(cy * rs * gg.y + bb.y);
  o.z = f2b(cz * rs * gg.z + bb.z);
  o.w = f2b(cw * rs * gg.w + bb.w);
  *(ushort4*)&ybf[base] = o;
}

// ---------------- output GEMM: O = Y x W_out^T, BM=64 BN=64, 4 blocks/CU ----------------
__global__ __launch_bounds__(256, 4) void k_out(const unsigned short* __restrict__ Y,
                                                const unsigned short* __restrict__ W,
                                                float* __restrict__ O) {
  __shared__ __align__(16) unsigned short As[2][64 * 64];  // 2x8KB
  __shared__ __align__(16) unsigned short Bs[2][64 * 64];  // 2x8KB
  const int tid = threadIdx.x;
  const int lane = tid & 63, wid = tid >> 6;
  const size_t row0 = (size_t)blockIdx.x * 64;
  const size_t col0 = (size_t)blockIdx.y * 64;
  f32x4 acc[4] = {};

  stage64x64(Y, row0, 0, As[0], tid);
  stage64x64(W, col0, 0, Bs[0], tid);
  __syncthreads();

  int cur = 0;
  const int r = lane & 15, kg = lane >> 4;
  for (int t = 0; t < 16; ++t) {
    if (t + 1 < 16) {
      stage64x64(Y, row0, (t + 1) * 64, As[cur ^ 1], tid);
      stage64x64(W, col0, (t + 1) * 64, Bs[cur ^ 1], tid);
    }
    #pragma unroll
    for (int ks = 0; ks < 2; ++ks) {
      const int arow = wid * 16 + r;
      bf16x8 a = *(const bf16x8*)&As[cur][arow * 64 + (((ks << 2) | kg) ^ (arow & 7)) * 8];
      bf16x8 b0, b1, b2, b3;
      b0 = *(const bf16x8*)&Bs[cur][(0 * 16 + r) * 64 + (((ks << 2) | kg) ^ ((0 * 16 + r) & 7)) * 8];
      b1 = *(const bf16x8*)&Bs[cur][(1 * 16 + r) * 64 + (((ks << 2) | kg) ^ ((1 * 16 + r) & 7)) * 8];
      b2 = *(const bf16x8*)&Bs[cur][(2 * 16 + r) * 64 + (((ks << 2) | kg) ^ ((2 * 16 + r) & 7)) * 8];
      b3 = *(const bf16x8*)&Bs[cur][(3 * 16 + r) * 64 + (((ks << 2) | kg) ^ ((3 * 16 + r) & 7)) * 8];
      acc[0] = __builtin_amdgcn_mfma_f32_16x16x32_bf16(a, b0, acc[0], 0, 0, 0);
      acc[1] = __builtin_amdgcn_mfma_f32_16x16x32_bf16(a, b1, acc[1], 0, 0, 0);
      acc[2] = __builtin_amdgcn_mfma_f32_16x16x32_bf16(a, b2, acc[2], 0, 0, 0);
      acc[3] = __builtin_amdgcn_mfma_f32_16x16x32_bf16(a, b3, acc[3], 0, 0, 0);
    }
    __syncthreads();
    cur ^= 1;
  }

  const int cr = lane >> 4, cc = lane & 15;
  #pragma unroll
  for (int n = 0; n < 4; ++n) {
    size_t orow = row0 + wid * 16 + cr * 4;
    float* op = O + orow * D_ + col0 + n * 16 + cc;
    #pragma unroll
    for (int j = 0; j < 4; ++j) op[(size_t)j * D_] = acc[n][j];
  }
}

extern "C" void kernel_launch(void* const* d_in, const int* in_sizes, int n_in,
                              void* d_out, int out_size, void* d_ws, size_t ws_size,
                              hipStream_t stream) {
  const float* x     = (const float*)d_in[0];
  const float* W_dtw = (const float*)d_in[1];
  const float* W_dt  = (const float*)d_in[2];
  const float* b_dt  = (const float*)d_in[3];
  const float* A_log = (const float*)d_in[4];
  const float* W_B   = (const float*)d_in[5];
  const float* W_C   = (const float*)d_in[6];
  const float* Dp    = (const float*)d_in[7];
  const float* ln_g  = (const float*)d_in[8];
  const float* ln_b  = (const float*)d_in[9];
  const float* W_out = (const float*)d_in[10];
  float* out = (float*)d_out;

  // ws_size = 256 MiB; ~73 MB used, all buffers dedicated.
  float* ws = (float*)d_ws;
  float* delta  = ws;                                   // 4,194,304 f
  float* ypre   = delta  + (size_t)BS_ * D_;            // 4,194,304 f
  float* Bm     = ypre   + (size_t)BS_ * D_;            //    65,536 f
  float* Cm     = Bm     + (size_t)BS_ * N_;            //    65,536 f
  float* hend   = Cm     + (size_t)BS_ * N_;            // 2,097,152 f
  float* hstart = hend   + (size_t)B_ * NC * D_ * N_;   // 2,097,152 f
  float* sdsum  = hstart + (size_t)B_ * NC * D_ * N_;   //   131,072 f
  unsigned short* xb   = (unsigned short*)(sdsum + (size_t)B_ * NC * D_);
  unsigned short* WBC  = xb   + (size_t)BS_ * D_;       // 32,768 u16
  unsigned short* weff = WBC  + (size_t)32 * D_;        // 1,048,576 u16
  unsigned short* wob  = weff + (size_t)D_ * D_;        // 1,048,576 u16
  unsigned short* ybf  = wob  + (size_t)D_ * D_;        // 4,194,304 u16

  k_castweff<<<dim3(6176), dim3(256), 0, stream>>>(x, W_B, W_C, W_out, W_dt, W_dtw,
                                                   xb, WBC, wob, weff);
  k_deltaBC<<<dim3(BS_ / 64, 17), dim3(256), 0, stream>>>(xb, weff, WBC, b_dt,
                                                          delta, Bm, Cm);
  {
    void* args[] = {(void*)&x, (void*)&delta, (void*)&Bm, (void*)&Cm,
                    (void*)&A_log, (void*)&Dp, (void*)&sdsum, (void*)&hend,
                    (void*)&hstart, (void*)&ypre};
    hipLaunchCooperativeKernel((void*)k_scanall, dim3(B_ * (NC / 2) * 16),
                               dim3(256), args, 0, stream);
  }
  k_ln<<<dim3(BS_), dim3(256), 0, stream>>>(ypre, ln_g, ln_b, ybf);
  k_out<<<dim3(BS_ / 64, D_ / 64), dim3(256), 0, stream>>>(ybf, wob, out);
}

// Round 12
// 125.418 us; speedup vs baseline: 3.0855x; 3.0855x over previous
//
#include <hip/hip_runtime.h>
#include <hip/hip_bf16.h>

#define B_ 2
#define S_ 2048
#define D_ 1024
#define N_ 16
#define R_ 64
#define NC 64          // number of scan chunks
#define CL 32          // chunk length  (NC*CL == S_)
#define BS_ (B_*S_)

typedef __attribute__((ext_vector_type(4))) float f32x4;
typedef __attribute__((ext_vector_type(8))) short bf16x8;
typedef __attribute__((ext_vector_type(8))) unsigned short u16x8;

__device__ __forceinline__ unsigned short f2b(float v) {
  unsigned u = __builtin_bit_cast(unsigned, v);
  unsigned r = ((u >> 16) & 1u) + 0x7FFFu;
  return (unsigned short)((u + r) >> 16);
}

__device__ __forceinline__ void gload_lds16(const void* g, void* l) {
  __builtin_amdgcn_global_load_lds(
      (const __attribute__((address_space(1))) unsigned int*)g,
      (__attribute__((address_space(3))) unsigned int*)l, 16, 0, 0);
}

// ---------------- casts + direct fp32 W_eff GEMM, one kernel (R11-verified) ----------------
// blocks 0..4095   : x     -> xb         (bf16 cast)
// blocks 4096..4111: W_B   -> WBC[0:16)  rows
// blocks 4112..4127: W_C   -> WBC[16:32) rows
// blocks 4128..5151: W_out -> wob
// blocks 5152..6175: weff[d][:] = W_dt[d][:] . W_dtw  (fp32 accum, bf16 out)
__global__ __launch_bounds__(256) void k_castweff(
    const float* __restrict__ x, const float* __restrict__ W_B,
    const float* __restrict__ W_C, const float* __restrict__ W_out,
    const float* __restrict__ W_dt, const float* __restrict__ W_dtw,
    unsigned short* __restrict__ xb, unsigned short* __restrict__ WBC,
    unsigned short* __restrict__ wob, unsigned short* __restrict__ weff) {
  const int blk = blockIdx.x, tid = threadIdx.x;
  if (blk < 5152) {
    const float* s; unsigned short* d; int base;
    if (blk < 4096)      { s = x;     d = xb;          base = 0; }
    else if (blk < 4112) { s = W_B;   d = WBC;         base = 4096; }
    else if (blk < 4128) { s = W_C;   d = WBC + 16384; base = 4112; }
    else                 { s = W_out; d = wob;         base = 4128; }
    int j = (blk - base) * 1024 + tid * 4;
    float4 v = *(const float4*)&s[j];
    ushort4 o;
    o.x = f2b(v.x); o.y = f2b(v.y); o.z = f2b(v.z); o.w = f2b(v.w);
    *(ushort4*)&d[j] = o;
  } else {
    const int dd = blk - 5152;                 // output row d
    const float* wdt = W_dt + (size_t)dd * R_;
    const int e4 = tid * 4;
    float a0 = 0.f, a1 = 0.f, a2 = 0.f, a3 = 0.f;
    #pragma unroll 8
    for (int r = 0; r < R_; ++r) {
      float w = wdt[r];                        // block-uniform -> scalar load
      float4 ww = *(const float4*)&W_dtw[(size_t)r * D_ + e4];
      a0 += w * ww.x; a1 += w * ww.y; a2 += w * ww.z; a3 += w * ww.w;
    }
    ushort4 o;
    o.x = f2b(a0); o.y = f2b(a1); o.z = f2b(a2); o.w = f2b(a3);
    *(ushort4*)&weff[(size_t)dd * D_ + e4] = o;
  }
}

// ---------------- shared staging helper: 64x64 u16 tile ----------------
__device__ __forceinline__ void stage64x64(const unsigned short* __restrict__ g,
                                           size_t row0, int k0,
                                           unsigned short* lds, int tid) {
  const int r = tid >> 3, s = tid & 7;
  #pragma unroll
  for (int i = 0; i < 2; ++i) {
    const int row = i * 32 + r;
    const int gs = s ^ (row & 7);
    gload_lds16(g + ((row0 + row) << 10) + k0 + (gs << 3), lds + row * 64 + s * 8);
  }
}

// ---------------- fused delta + B/C projection GEMM, BM=64 BN=64 ----------------
// grid (64, 17): by<16 -> delta[:, by*64..+63] = softplus(xb . weff^T + b_dt)
//                by==16 -> Bm,Cm = xb . WBC^T (32 cols)
// 4 blocks/CU co-resident (R9/R10 lesson). All acc indices literal (rule #20).
__global__ __launch_bounds__(256, 4) void k_deltaBC(
    const unsigned short* __restrict__ xb, const unsigned short* __restrict__ weff,
    const unsigned short* __restrict__ WBC, const float* __restrict__ b_dt,
    float* __restrict__ delta, float* __restrict__ Bm, float* __restrict__ Cm) {
  __shared__ __align__(16) unsigned short As[2][64 * 64];  // 2x8KB
  __shared__ __align__(16) unsigned short Bs[2][64 * 64];  // 2x8KB
  const int tid = threadIdx.x;
  const int lane = tid & 63, wid = tid >> 6;
  const size_t row0 = (size_t)blockIdx.x * 64;
  const int by = blockIdx.y;
  const bool bc = (by == 16);
  f32x4 acc[4] = {};

  auto stageB = [&](int buf, int k0) {
    if (!bc) {
      stage64x64(weff, (size_t)by * 64, k0, Bs[buf], tid);
    } else {
      const int row = tid >> 3, s = tid & 7;       // 32 rows, 1 load/thread
      const int gs = s ^ (row & 7);
      gload_lds16(WBC + (size_t)row * D_ + k0 + (gs << 3), Bs[buf] + row * 64 + s * 8);
    }
  };

  stage64x64(xb, row0, 0, As[0], tid);
  stageB(0, 0);
  __syncthreads();

  int cur = 0;
  const int r = lane & 15, kg = lane >> 4;
  for (int t = 0; t < 16; ++t) {
    if (t + 1 < 16) {
      stage64x64(xb, row0, (t + 1) * 64, As[cur ^ 1], tid);
      stageB(cur ^ 1, (t + 1) * 64);
    }
    if (!bc) {
      #pragma unroll
      for (int ks = 0; ks < 2; ++ks) {
        const int arow = wid * 16 + r;
        bf16x8 a = *(const bf16x8*)&As[cur][arow * 64 + (((ks << 2) | kg) ^ (arow & 7)) * 8];
        bf16x8 b0, b1, b2, b3;
        b0 = *(const bf16x8*)&Bs[cur][(0 * 16 + r) * 64 + (((ks << 2) | kg) ^ ((0 * 16 + r) & 7)) * 8];
        b1 = *(const bf16x8*)&Bs[cur][(1 * 16 + r) * 64 + (((ks << 2) | kg) ^ ((1 * 16 + r) & 7)) * 8];
        b2 = *(const bf16x8*)&Bs[cur][(2 * 16 + r) * 64 + (((ks << 2) | kg) ^ ((2 * 16 + r) & 7)) * 8];
        b3 = *(const bf16x8*)&Bs[cur][(3 * 16 + r) * 64 + (((ks << 2) | kg) ^ ((3 * 16 + r) & 7)) * 8];
        acc[0] = __builtin_amdgcn_mfma_f32_16x16x32_bf16(a, b0, acc[0], 0, 0, 0);
        acc[1] = __builtin_amdgcn_mfma_f32_16x16x32_bf16(a, b1, acc[1], 0, 0, 0);
        acc[2] = __builtin_amdgcn_mfma_f32_16x16x32_bf16(a, b2, acc[2], 0, 0, 0);
        acc[3] = __builtin_amdgcn_mfma_f32_16x16x32_bf16(a, b3, acc[3], 0, 0, 0);
      }
    } else {
      #pragma unroll
      for (int ks = 0; ks < 2; ++ks) {
        const int arow = wid * 16 + r;
        bf16x8 a = *(const bf16x8*)&As[cur][arow * 64 + (((ks << 2) | kg) ^ (arow & 7)) * 8];
        bf16x8 b0, b1;
        b0 = *(const bf16x8*)&Bs[cur][(0 * 16 + r) * 64 + (((ks << 2) | kg) ^ ((0 * 16 + r) & 7)) * 8];
        b1 = *(const bf16x8*)&Bs[cur][(1 * 16 + r) * 64 + (((ks << 2) | kg) ^ ((1 * 16 + r) & 7)) * 8];
        acc[0] = __builtin_amdgcn_mfma_f32_16x16x32_bf16(a, b0, acc[0], 0, 0, 0);
        acc[1] = __builtin_amdgcn_mfma_f32_16x16x32_bf16(a, b1, acc[1], 0, 0, 0);
      }
    }
    __syncthreads();
    cur ^= 1;
  }

  const int cr = lane >> 4, cc = lane & 15;
  if (!bc) {
    #pragma unroll
    for (int n = 0; n < 4; ++n) {
      const int d = by * 64 + n * 16 + cc;
      const float bd = b_dt[d];
      #pragma unroll
      for (int j = 0; j < 4; ++j) {
        size_t trow = row0 + wid * 16 + cr * 4 + j;
        float v = acc[n][j] + bd;
        float sp = fmaxf(v, 0.f) + log1pf(__expf(-fabsf(v)));
        delta[trow * D_ + d] = sp;
      }
    }
  } else {
    #pragma unroll
    for (int n = 0; n < 2; ++n) {
      const int col = n * 16 + cc;
      #pragma unroll
      for (int j = 0; j < 4; ++j) {
        size_t trow = row0 + wid * 16 + cr * 4 + j;
        float v = acc[n][j];
        if (col < 16) Bm[trow * N_ + col] = v;
        else          Cm[trow * N_ + col - 16] = v;
      }
    }
  }
}

// ---------------- scan phase 1: per-chunk hend + delta-sum ----------------
__global__ __launch_bounds__(256) void k_scan1(
    const float* __restrict__ x, const float* __restrict__ delta,
    const float* __restrict__ Bm, const float* __restrict__ A_log,
    float* __restrict__ sdsum, float* __restrict__ hend) {
  __shared__ __align__(16) float sd[CL][64];
  __shared__ __align__(16) float sx[CL][64];
  __shared__ __align__(16) float sB[CL][N_];
  const int tid = threadIdx.x;
  const int db = blockIdx.x & 15;
  const int c  = (blockIdx.x >> 4) & (NC - 1);
  const int b  = blockIdx.x >> 10;
  const int d0 = db * 64;
  const size_t tokbase = (size_t)(b * S_ + c * CL);

  {
    int s = tid >> 4, jf = (tid & 15) * 4;
    size_t g = (tokbase + s) * D_ + d0 + jf;
    gload_lds16(&delta[g], &sd[s][jf]);
    gload_lds16(&x[g],     &sx[s][jf]);
    gload_lds16(&delta[g + (size_t)16 * D_], &sd[s + 16][jf]);
    gload_lds16(&x[g + (size_t)16 * D_],     &sx[s + 16][jf]);
    if (tid < 128) {
      int s2 = tid >> 2, nf = (tid & 3) * 4;
      gload_lds16(&Bm[(tokbase + s2) * N_ + nf], &sB[s2][nf]);
    }
  }
  const int nq = tid & 3, dl = tid >> 2;
  const int d = d0 + dl;
  float4 av = *(const float4*)&A_log[(size_t)d * N_ + nq * 4];
  float Ad0 = -__expf(av.x), Ad1 = -__expf(av.y);
  float Ad2 = -__expf(av.z), Ad3 = -__expf(av.w);
  __syncthreads();

  float sds = 0.f;
  float h0 = 0.f, h1 = 0.f, h2 = 0.f, h3 = 0.f;
  #pragma unroll 8
  for (int s = 0; s < CL; ++s) {
    float dlt = sd[s][dl];
    float dbx = dlt * sx[s][dl];
    sds += dlt;
    float4 Bv = *(const float4*)&sB[s][nq * 4];
    float da0 = __expf(dlt * Ad0), da1 = __expf(dlt * Ad1);
    float da2 = __expf(dlt * Ad2), da3 = __expf(dlt * Ad3);
    h0 = da0 * h0 + dbx * Bv.x;
    h1 = da1 * h1 + dbx * Bv.y;
    h2 = da2 * h2 + dbx * Bv.z;
    h3 = da3 * h3 + dbx * Bv.w;
  }
  size_t o = (((size_t)(b * NC + c)) * D_ + d) * N_ + nq * 4;
  *(float4*)&hend[o] = make_float4(h0, h1, h2, h3);
  if (nq == 0) sdsum[(size_t)(b * NC + c) * D_ + d] = sds;
}

// ---------------- scan phase 2: hierarchical chunk-summary scan ----------------
__global__ __launch_bounds__(256) void k_scan2(
    const float* __restrict__ sdsum, const float* __restrict__ hend,
    const float* __restrict__ A_log, float* __restrict__ hstart) {
  const int tid = threadIdx.x;
  const int o  = tid & 7;
  const int n  = (tid >> 3) & 15;
  const int dl = tid >> 7;                 // 0..1
  const int d2 = blockIdx.x & 511;
  const int b  = blockIdx.x >> 9;
  const int d  = d2 * 2 + dl;
  const float Ad = -__expf(A_log[(size_t)d * N_ + n]);

  float ap8[8], he8[8];
  float A_loc = 1.f, H_loc = 0.f;
  #pragma unroll
  for (int k = 0; k < 8; ++k) {
    const int c = o * 8 + k;
    float sds = sdsum[(size_t)(b * NC + c) * D_ + d];
    float ap = __expf(Ad * sds);
    float he = hend[((size_t)(b * NC + c) * D_ + d) * N_ + n];
    ap8[k] = ap; he8[k] = he;
    A_loc *= ap;
    H_loc = ap * H_loc + he;
  }
  float h = 0.f;
  const int gb = (tid & 63) & ~7;
  #pragma unroll
  for (int j = 0; j < 7; ++j) {
    float Aj = __shfl(A_loc, gb | j, 64);
    float Hj = __shfl(H_loc, gb | j, 64);
    if (o > j) h = Aj * h + Hj;
  }
  #pragma unroll
  for (int k = 0; k < 8; ++k) {
    const int c = o * 8 + k;
    hstart[((size_t)(b * NC + c) * D_ + d) * N_ + n] = h;
    h = ap8[k] * h + he8[k];
  }
}

// ---------------- scan phase 3: recompute + y + fused residual ----------------
__global__ __launch_bounds__(256) void k_scan3(
    const float* __restrict__ x, const float* __restrict__ delta,
    const float* __restrict__ Bm, const float* __restrict__ Cm,
    const float* __restrict__ A_log, const float* __restrict__ hstart,
    const float* __restrict__ Dp, float* __restrict__ ypre) {
  __shared__ __align__(16) float sd[CL][64];
  __shared__ __align__(16) float sx[CL][64];
  __shared__ __align__(16) float sB[CL][N_];
  __shared__ __align__(16) float sC[CL][N_];
  __shared__ __align__(16) float sy[CL][64];
  const int tid = threadIdx.x;
  const int db = blockIdx.x & 15;
  const int c  = (blockIdx.x >> 4) & (NC - 1);
  const int b  = blockIdx.x >> 10;
  const int d0 = db * 64;
  const size_t tokbase = (size_t)(b * S_ + c * CL);

  {
    int s = tid >> 4, jf = (tid & 15) * 4;
    size_t g = (tokbase + s) * D_ + d0 + jf;
    gload_lds16(&delta[g], &sd[s][jf]);
    gload_lds16(&x[g],     &sx[s][jf]);
    gload_lds16(&delta[g + (size_t)16 * D_], &sd[s + 16][jf]);
    gload_lds16(&x[g + (size_t)16 * D_],     &sx[s + 16][jf]);
    if (tid < 128) {
      int s2 = tid >> 2, nf = (tid & 3) * 4;
      gload_lds16(&Bm[(tokbase + s2) * N_ + nf], &sB[s2][nf]);
      gload_lds16(&Cm[(tokbase + s2) * N_ + nf], &sC[s2][nf]);
    }
  }
  const int nq = tid & 3, dl = tid >> 2;
  const int d = d0 + dl;
  float4 av = *(const float4*)&A_log[(size_t)d * N_ + nq * 4];
  float Ad0 = -__expf(av.x), Ad1 = -__expf(av.y);
  float Ad2 = -__expf(av.z), Ad3 = -__expf(av.w);
  float h0, h1, h2, h3;
  {
    size_t o = (((size_t)(b * NC + c)) * D_ + d) * N_ + nq * 4;
    float4 v = *(const float4*)&hstart[o];
    h0 = v.x; h1 = v.y; h2 = v.z; h3 = v.w;
  }
  const float Dpd = Dp[d];
  __syncthreads();

  #pragma unroll 8
  for (int s = 0; s < CL; ++s) {
    float dlt = sd[s][dl];
    float xv  = sx[s][dl];
    float dbx = dlt * xv;
    float4 Bv = *(const float4*)&sB[s][nq * 4];
    float4 Cv = *(const float4*)&sC[s][nq * 4];
    float da0 = __expf(dlt * Ad0), da1 = __expf(dlt * Ad1);
    float da2 = __expf(dlt * Ad2), da3 = __expf(dlt * Ad3);
    h0 = da0 * h0 + dbx * Bv.x;
    h1 = da1 * h1 + dbx * Bv.y;
    h2 = da2 * h2 + dbx * Bv.z;
    h3 = da3 * h3 + dbx * Bv.w;
    float y = h0 * Cv.x + h1 * Cv.y + h2 * Cv.z + h3 * Cv.w;
    y += __shfl_xor(y, 1);
    y += __shfl_xor(y, 2);
    if (nq == 0) sy[s][dl] = y + Dpd * xv;
  }
  __syncthreads();
  {
    int s = tid >> 3, j = (tid & 7) * 8;
    size_t g = (tokbase + s) * D_ + d0 + j;
    *(float4*)&ypre[g]     = *(float4*)&sy[s][j];
    *(float4*)&ypre[g + 4] = *(float4*)&sy[s][j + 4];
  }
}

// ---------------- layernorm (residual already fused) -> bf16 y ----------------
__device__ __forceinline__ float block_sum256(float v, float* sm) {
  #pragma unroll
  for (int o = 32; o > 0; o >>= 1) v += __shfl_down(v, o, 64);
  int w = threadIdx.x >> 6;
  __syncthreads();
  if ((threadIdx.x & 63) == 0) sm[w] = v;
  __syncthreads();
  return (sm[0] + sm[1]) + (sm[2] + sm[3]);
}

__global__ __launch_bounds__(256) void k_ln(
    const float* __restrict__ ypre, const float* __restrict__ g,
    const float* __restrict__ bta, unsigned short* __restrict__ ybf) {
  __shared__ float sm[4];
  const int t = blockIdx.x;
  const int tid = threadIdx.x;
  size_t base = (size_t)t * D_ + tid * 4;
  float4 v = *(const float4*)&ypre[base];
  float s1 = block_sum256(v.x + v.y + v.z + v.w, sm);
  float mu = s1 * (1.f / D_);
  float cx = v.x - mu, cy = v.y - mu, cz = v.z - mu, cw = v.w - mu;
  float s2 = block_sum256(cx*cx + cy*cy + cz*cz + cw*cw, sm);
  float rs = rsqrtf(s2 * (1.f / D_) + 1e-5f);
  float4 gg = *(const float4*)&g[tid * 4];
  float4 bb = *(const float4*)&bta[tid * 4];
  ushort4 o;
  o.x = f2b(cx * rs * gg.x + bb.x);
  o.y = f2b(cy * rs * gg.y + bb.y);
  o.z = f2b(cz * rs * gg.z + bb.z);
  o.w = f2b(cw * rs * gg.w + bb.w);
  *(ushort4*)&ybf[base] = o;
}

// ---------------- output GEMM: O = Y x W_out^T, BM=64 BN=64, 4 blocks/CU ----------------
__global__ __launch_bounds__(256, 4) void k_out(const unsigned short* __restrict__ Y,
                                                const unsigned short* __restrict__ W,
                                                float* __restrict__ O) {
  __shared__ __align__(16) unsigned short As[2][64 * 64];  // 2x8KB
  __shared__ __align__(16) unsigned short Bs[2][64 * 64];  // 2x8KB
  const int tid = threadIdx.x;
  const int lane = tid & 63, wid = tid >> 6;
  const size_t row0 = (size_t)blockIdx.x * 64;
  const size_t col0 = (size_t)blockIdx.y * 64;
  f32x4 acc[4] = {};

  stage64x64(Y, row0, 0, As[0], tid);
  stage64x64(W, col0, 0, Bs[0], tid);
  __syncthreads();

  int cur = 0;
  const int r = lane & 15, kg = lane >> 4;
  for (int t = 0; t < 16; ++t) {
    if (t + 1 < 16) {
      stage64x64(Y, row0, (t + 1) * 64, As[cur ^ 1], tid);
      stage64x64(W, col0, (t + 1) * 64, Bs[cur ^ 1], tid);
    }
    #pragma unroll
    for (int ks = 0; ks < 2; ++ks) {
      const int arow = wid * 16 + r;
      bf16x8 a = *(const bf16x8*)&As[cur][arow * 64 + (((ks << 2) | kg) ^ (arow & 7)) * 8];
      bf16x8 b0, b1, b2, b3;
      b0 = *(const bf16x8*)&Bs[cur][(0 * 16 + r) * 64 + (((ks << 2) | kg) ^ ((0 * 16 + r) & 7)) * 8];
      b1 = *(const bf16x8*)&Bs[cur][(1 * 16 + r) * 64 + (((ks << 2) | kg) ^ ((1 * 16 + r) & 7)) * 8];
      b2 = *(const bf16x8*)&Bs[cur][(2 * 16 + r) * 64 + (((ks << 2) | kg) ^ ((2 * 16 + r) & 7)) * 8];
      b3 = *(const bf16x8*)&Bs[cur][(3 * 16 + r) * 64 + (((ks << 2) | kg) ^ ((3 * 16 + r) & 7)) * 8];
      acc[0] = __builtin_amdgcn_mfma_f32_16x16x32_bf16(a, b0, acc[0], 0, 0, 0);
      acc[1] = __builtin_amdgcn_mfma_f32_16x16x32_bf16(a, b1, acc[1], 0, 0, 0);
      acc[2] = __builtin_amdgcn_mfma_f32_16x16x32_bf16(a, b2, acc[2], 0, 0, 0);
      acc[3] = __builtin_amdgcn_mfma_f32_16x16x32_bf16(a, b3, acc[3], 0, 0, 0);
    }
    __syncthreads();
    cur ^= 1;
  }

  const int cr = lane >> 4, cc = lane & 15;
  #pragma unroll
  for (int n = 0; n < 4; ++n) {
    size_t orow = row0 + wid * 16 + cr * 4;
    float* op = O + orow * D_ + col0 + n * 16 + cc;
    #pragma unroll
    for (int j = 0; j < 4; ++j) op[(size_t)j * D_] = acc[n][j];
  }
}

extern "C" void kernel_launch(void* const* d_in, const int* in_sizes, int n_in,
                              void* d_out, int out_size, void* d_ws, size_t ws_size,
                              hipStream_t stream) {
  const float* x     = (const float*)d_in[0];
  const float* W_dtw = (const float*)d_in[1];
  const float* W_dt  = (const float*)d_in[2];
  const float* b_dt  = (const float*)d_in[3];
  const float* A_log = (const float*)d_in[4];
  const float* W_B   = (const float*)d_in[5];
  const float* W_C   = (const float*)d_in[6];
  const float* Dp    = (const float*)d_in[7];
  const float* ln_g  = (const float*)d_in[8];
  const float* ln_b  = (const float*)d_in[9];
  const float* W_out = (const float*)d_in[10];
  float* out = (float*)d_out;

  // ws_size = 256 MiB; ~73 MB used, all buffers dedicated.
  float* ws = (float*)d_ws;
  float* delta  = ws;                                   // 4,194,304 f
  float* ypre   = delta  + (size_t)BS_ * D_;            // 4,194,304 f
  float* Bm     = ypre   + (size_t)BS_ * D_;            //    65,536 f
  float* Cm     = Bm     + (size_t)BS_ * N_;            //    65,536 f
  float* hend   = Cm     + (size_t)BS_ * N_;            // 2,097,152 f
  float* hstart = hend   + (size_t)B_ * NC * D_ * N_;   // 2,097,152 f
  float* sdsum  = hstart + (size_t)B_ * NC * D_ * N_;   //   131,072 f
  unsigned short* xb   = (unsigned short*)(sdsum + (size_t)B_ * NC * D_);
  unsigned short* WBC  = xb   + (size_t)BS_ * D_;       // 32,768 u16
  unsigned short* weff = WBC  + (size_t)32 * D_;        // 1,048,576 u16
  unsigned short* wob  = weff + (size_t)D_ * D_;        // 1,048,576 u16
  unsigned short* ybf  = wob  + (size_t)D_ * D_;        // 4,194,304 u16

  k_castweff<<<dim3(6176), dim3(256), 0, stream>>>(x, W_B, W_C, W_out, W_dt, W_dtw,
                                                   xb, WBC, wob, weff);
  k_deltaBC<<<dim3(BS_ / 64, 17), dim3(256), 0, stream>>>(xb, weff, WBC, b_dt,
                                                          delta, Bm, Cm);
  k_scan1<<<dim3(B_ * NC * (D_ / 64)), dim3(256), 0, stream>>>(x, delta, Bm, A_log,
                                                               sdsum, hend);
  k_scan2<<<dim3(B_ * (D_ / 2)), dim3(256), 0, stream>>>(sdsum, hend, A_log, hstart);
  k_scan3<<<dim3(B_ * NC * (D_ / 64)), dim3(256), 0, stream>>>(x, delta, Bm, Cm,
                                                               A_log, hstart, Dp, ypre);
  k_ln<<<dim3(BS_), dim3(256), 0, stream>>>(ypre, ln_g, ln_b, ybf);
  k_out<<<dim3(BS_ / 64, D_ / 64), dim3(256), 0, stream>>>(ybf, wob, out);
}

// Round 13
// 111.916 us; speedup vs baseline: 3.4577x; 1.1206x over previous
//
#include <hip/hip_runtime.h>
#include <hip/hip_bf16.h>

#define B_ 2
#define S_ 2048
#define D_ 1024
#define N_ 16
#define R_ 64
#define NC 64          // number of scan chunks
#define CL 32          // chunk length  (NC*CL == S_)
#define BS_ (B_*S_)
#define KSPLIT 8

typedef __attribute__((ext_vector_type(4))) float f32x4;
typedef __attribute__((ext_vector_type(8))) short bf16x8;
typedef __attribute__((ext_vector_type(8))) unsigned short u16x8;

__device__ __forceinline__ unsigned short f2b(float v) {
  unsigned u = __builtin_bit_cast(unsigned, v);
  unsigned r = ((u >> 16) & 1u) + 0x7FFFu;
  return (unsigned short)((u + r) >> 16);
}

__device__ __forceinline__ void gload_lds16(const void* g, void* l) {
  __builtin_amdgcn_global_load_lds(
      (const __attribute__((address_space(1))) unsigned int*)g,
      (__attribute__((address_space(3))) unsigned int*)l, 16, 0, 0);
}

// ---------------- fp32 -> bf16 cast for WEIGHTS (R5-verified) ----------------
//  [0,      65536)  W_dtw -> Wcat rows 0..63
//  [65536,  81920)  W_B   -> Wcat rows 64..79
//  [81920,  98304)  W_C   -> Wcat rows 80..95
//  [98304, 163840)  W_dt  -> wdtb
//  [163840,1212416) W_out -> wob
__global__ __launch_bounds__(256) void k_castall(
    const float* __restrict__ W_dtw, const float* __restrict__ W_B,
    const float* __restrict__ W_C, const float* __restrict__ W_dt,
    const float* __restrict__ W_out,
    unsigned short* __restrict__ Wcat, unsigned short* __restrict__ wdtb,
    unsigned short* __restrict__ wob) {
  int i = (blockIdx.x * 256 + threadIdx.x) * 4;   // grid covers 1212416 elems
  const float* s; unsigned short* d; int off;
  if (i < 65536)       { s = W_dtw; d = Wcat;         off = 0; }
  else if (i < 81920)  { s = W_B;   d = Wcat + 65536; off = 65536; }
  else if (i < 98304)  { s = W_C;   d = Wcat + 81920; off = 81920; }
  else if (i < 163840) { s = W_dt;  d = wdtb;         off = 98304; }
  else                 { s = W_out; d = wob;          off = 163840; }
  int j = i - off;
  float4 v = *(const float4*)&s[j];
  ushort4 o;
  o.x = f2b(v.x); o.y = f2b(v.y); o.z = f2b(v.z); o.w = f2b(v.w);
  *(ushort4*)&d[j] = o;
}

// ---------------- fused x-projection GEMM, K-split by 8 (R5-verified) ----------------
// [4096,1024] x [1024,96] -> fp32 partials part[ksplit][4096][96]
__global__ __launch_bounds__(256, 2) void k_proj(
    const float* __restrict__ x, const unsigned short* __restrict__ Wcat,
    float* __restrict__ part) {
  __shared__ __align__(16) unsigned short Xs[2][64 * 64];   // 2x8KB
  __shared__ __align__(16) unsigned short Ws[2][96 * 64];   // 2x12KB
  const int tid = threadIdx.x;
  const int lane = tid & 63, w = tid >> 6;
  const size_t row0 = (size_t)blockIdx.x * 64;
  const int kbase = blockIdx.y * (D_ / KSPLIT);             // 128-wide K slice
  f32x4 acc[6] = {};

  auto stage = [&](int buf, int k0) {
    // x tile 64x64: reg-stage fp32 -> bf16, swizzled ds_write
    #pragma unroll
    for (int i = 0; i < 2; ++i) {
      int id = i * 256 + tid; int row = id >> 3, s = id & 7;
      const float* gp = &x[(row0 + row) * D_ + k0 + s * 8];
      float4 v0 = *(const float4*)gp;
      float4 v1 = *(const float4*)(gp + 4);
      u16x8 u;
      u[0] = f2b(v0.x); u[1] = f2b(v0.y); u[2] = f2b(v0.z); u[3] = f2b(v0.w);
      u[4] = f2b(v1.x); u[5] = f2b(v1.y); u[6] = f2b(v1.z); u[7] = f2b(v1.w);
      *(u16x8*)&Xs[buf][row * 64 + ((s ^ (row & 7)) << 3)] = u;
    }
    // W tile 96x64: async, pre-swizzled source + linear LDS dest
    #pragma unroll
    for (int i = 0; i < 3; ++i) {
      int id = i * 256 + tid; int row = id >> 3, s = id & 7;
      gload_lds16(Wcat + (size_t)row * D_ + k0 + ((s ^ (row & 7)) << 3),
                  Ws[buf] + row * 64 + s * 8);
    }
  };
  stage(0, kbase);
  __syncthreads();
  int cur = 0;
  const int r = lane & 15, kg = lane >> 4;
  for (int t = 0; t < 2; ++t) {
    if (t < 1) stage(cur ^ 1, kbase + 64);
    #pragma unroll
    for (int ks = 0; ks < 2; ++ks) {
      const int arow = w * 16 + r;
      bf16x8 a = *(const bf16x8*)&Xs[cur][arow * 64 + ((((ks << 2) | kg) ^ (arow & 7)) << 3)];
      #pragma unroll
      for (int nt = 0; nt < 6; ++nt) {
        const int brow = nt * 16 + r;
        bf16x8 b = *(const bf16x8*)&Ws[cur][brow * 64 + ((((ks << 2) | kg) ^ (brow & 7)) << 3)];
        acc[nt] = __builtin_amdgcn_mfma_f32_16x16x32_bf16(a, b, acc[nt], 0, 0, 0);
      }
    }
    __syncthreads();
    cur ^= 1;
  }
  const int cr = lane >> 4, cc = lane & 15;
  float* pb = part + (size_t)blockIdx.y * (BS_ * 96);
  #pragma unroll
  for (int nt = 0; nt < 6; ++nt)
    #pragma unroll
    for (int j = 0; j < 4; ++j)
      pb[(row0 + w * 16 + cr * 4 + j) * 96 + nt * 16 + cc] = acc[nt][j];
}

// reduce 8 K-split partials -> dtb (bf16), Bm, Cm (fp32)  (R5-verified)
__global__ __launch_bounds__(256) void k_projred(
    const float* __restrict__ part, unsigned short* __restrict__ dtb,
    float* __restrict__ Bm, float* __restrict__ Cm) {
  int e = blockIdx.x * 256 + threadIdx.x;        // < 4096*96
  int row = e / 96, col = e - row * 96;
  float s = 0.f;
  #pragma unroll
  for (int p = 0; p < KSPLIT; ++p) s += part[e + (size_t)p * (BS_ * 96)];
  if (col < 64)      dtb[row * R_ + col] = f2b(s);
  else if (col < 80) Bm[row * N_ + col - 64] = s;
  else               Cm[row * N_ + col - 80] = s;
}

// ---------------- delta GEMM: softplus(dt[4096,64] x W_dt^T[64,1024] + b) (R5-verified) ----
__global__ __launch_bounds__(256) void k_delta(
    const unsigned short* __restrict__ dtb, const unsigned short* __restrict__ wdtb,
    const float* __restrict__ b_dt, float* __restrict__ delta) {
  __shared__ __align__(16) unsigned short As[128 * 64];  // 16KB
  __shared__ __align__(16) unsigned short Bs[128 * 64];  // 16KB
  const int tid = threadIdx.x;
  const int lane = tid & 63, wid = tid >> 6;
  const int wr = wid >> 1, wc = wid & 1;
  const size_t row0 = (size_t)blockIdx.x * 128;
  const size_t col0 = (size_t)blockIdx.y * 128;
  f32x4 acc[4][4] = {};

  {
    const int r = tid >> 3, s = tid & 7;
    #pragma unroll
    for (int i = 0; i < 4; ++i) {
      const int row = i * 32 + r;
      const int gs = s ^ (row & 7);
      gload_lds16(dtb + (row0 + row) * R_ + gs * 8, As + row * 64 + s * 8);
      gload_lds16(wdtb + (col0 + row) * R_ + gs * 8, Bs + row * 64 + s * 8);
    }
  }
  __syncthreads();
  const int r = lane & 15, kg = lane >> 4;
  #pragma unroll
  for (int ks = 0; ks < 2; ++ks) {
    bf16x8 a[4], b[4];
    #pragma unroll
    for (int m = 0; m < 4; ++m) {
      const int arow = wr * 64 + m * 16 + r;
      a[m] = *(const bf16x8*)&As[arow * 64 + (((ks << 2) | kg) ^ (arow & 7)) * 8];
    }
    #pragma unroll
    for (int n = 0; n < 4; ++n) {
      const int brow = wc * 64 + n * 16 + r;
      b[n] = *(const bf16x8*)&Bs[brow * 64 + (((ks << 2) | kg) ^ (brow & 7)) * 8];
    }
    #pragma unroll
    for (int m = 0; m < 4; ++m)
      #pragma unroll
      for (int n = 0; n < 4; ++n)
        acc[m][n] = __builtin_amdgcn_mfma_f32_16x16x32_bf16(a[m], b[n], acc[m][n], 0, 0, 0);
  }
  const int cr = lane >> 4, cc = lane & 15;
  #pragma unroll
  for (int m = 0; m < 4; ++m) {
    #pragma unroll
    for (int n = 0; n < 4; ++n) {
      const int d = (int)col0 + wc * 64 + n * 16 + cc;
      const float bd = b_dt[d];
      #pragma unroll
      for (int j = 0; j < 4; ++j) {
        size_t trow = row0 + wr * 64 + m * 16 + cr * 4 + j;
        float v = acc[m][n][j] + bd;
        float sp = fmaxf(v, 0.f) + log1pf(__expf(-fabsf(v)));
        delta[trow * D_ + d] = sp;
      }
    }
  }
}

// ---------------- scan phase 1: per-chunk hend + delta-sum (R8-verified) ----------------
__global__ __launch_bounds__(256) void k_scan1(
    const float* __restrict__ x, const float* __restrict__ delta,
    const float* __restrict__ Bm, const float* __restrict__ A_log,
    float* __restrict__ sdsum, float* __restrict__ hend) {
  __shared__ __align__(16) float sd[CL][64];
  __shared__ __align__(16) float sx[CL][64];
  __shared__ __align__(16) float sB[CL][N_];
  const int tid = threadIdx.x;
  const int db = blockIdx.x & 15;
  const int c  = (blockIdx.x >> 4) & (NC - 1);
  const int b  = blockIdx.x >> 10;
  const int d0 = db * 64;
  const size_t tokbase = (size_t)(b * S_ + c * CL);

  {
    int s = tid >> 4, jf = (tid & 15) * 4;
    size_t g = (tokbase + s) * D_ + d0 + jf;
    gload_lds16(&delta[g], &sd[s][jf]);
    gload_lds16(&x[g],     &sx[s][jf]);
    gload_lds16(&delta[g + (size_t)16 * D_], &sd[s + 16][jf]);
    gload_lds16(&x[g + (size_t)16 * D_],     &sx[s + 16][jf]);
    if (tid < 128) {
      int s2 = tid >> 2, nf = (tid & 3) * 4;
      gload_lds16(&Bm[(tokbase + s2) * N_ + nf], &sB[s2][nf]);
    }
  }
  const int nq = tid & 3, dl = tid >> 2;
  const int d = d0 + dl;
  float4 av = *(const float4*)&A_log[(size_t)d * N_ + nq * 4];
  float Ad0 = -__expf(av.x), Ad1 = -__expf(av.y);
  float Ad2 = -__expf(av.z), Ad3 = -__expf(av.w);
  __syncthreads();

  float sds = 0.f;
  float h0 = 0.f, h1 = 0.f, h2 = 0.f, h3 = 0.f;
  #pragma unroll 8
  for (int s = 0; s < CL; ++s) {
    float dlt = sd[s][dl];
    float dbx = dlt * sx[s][dl];
    sds += dlt;
    float4 Bv = *(const float4*)&sB[s][nq * 4];
    float da0 = __expf(dlt * Ad0), da1 = __expf(dlt * Ad1);
    float da2 = __expf(dlt * Ad2), da3 = __expf(dlt * Ad3);
    h0 = da0 * h0 + dbx * Bv.x;
    h1 = da1 * h1 + dbx * Bv.y;
    h2 = da2 * h2 + dbx * Bv.z;
    h3 = da3 * h3 + dbx * Bv.w;
  }
  size_t o = (((size_t)(b * NC + c)) * D_ + d) * N_ + nq * 4;
  *(float4*)&hend[o] = make_float4(h0, h1, h2, h3);
  if (nq == 0) sdsum[(size_t)(b * NC + c) * D_ + d] = sds;
}

// ---------------- scan phase 2: hierarchical chunk-summary scan (R9-verified) ----------------
__global__ __launch_bounds__(256) void k_scan2(
    const float* __restrict__ sdsum, const float* __restrict__ hend,
    const float* __restrict__ A_log, float* __restrict__ hstart) {
  const int tid = threadIdx.x;
  const int o  = tid & 7;
  const int n  = (tid >> 3) & 15;
  const int dl = tid >> 7;                 // 0..1
  const int d2 = blockIdx.x & 511;
  const int b  = blockIdx.x >> 9;
  const int d  = d2 * 2 + dl;
  const float Ad = -__expf(A_log[(size_t)d * N_ + n]);

  float ap8[8], he8[8];
  float A_loc = 1.f, H_loc = 0.f;
  #pragma unroll
  for (int k = 0; k < 8; ++k) {
    const int c = o * 8 + k;
    float sds = sdsum[(size_t)(b * NC + c) * D_ + d];
    float ap = __expf(Ad * sds);
    float he = hend[((size_t)(b * NC + c) * D_ + d) * N_ + n];
    ap8[k] = ap; he8[k] = he;
    A_loc *= ap;
    H_loc = ap * H_loc + he;
  }
  float h = 0.f;
  const int gb = (tid & 63) & ~7;
  #pragma unroll
  for (int j = 0; j < 7; ++j) {
    float Aj = __shfl(A_loc, gb | j, 64);
    float Hj = __shfl(H_loc, gb | j, 64);
    if (o > j) h = Aj * h + Hj;
  }
  #pragma unroll
  for (int k = 0; k < 8; ++k) {
    const int c = o * 8 + k;
    hstart[((size_t)(b * NC + c) * D_ + d) * N_ + n] = h;
    h = ap8[k] * h + he8[k];
  }
}

// ---------------- scan phase 3: recompute + y + fused residual (R8-verified) ----------------
__global__ __launch_bounds__(256) void k_scan3(
    const float* __restrict__ x, const float* __restrict__ delta,
    const float* __restrict__ Bm, const float* __restrict__ Cm,
    const float* __restrict__ A_log, const float* __restrict__ hstart,
    const float* __restrict__ Dp, float* __restrict__ ypre) {
  __shared__ __align__(16) float sd[CL][64];
  __shared__ __align__(16) float sx[CL][64];
  __shared__ __align__(16) float sB[CL][N_];
  __shared__ __align__(16) float sC[CL][N_];
  __shared__ __align__(16) float sy[CL][64];
  const int tid = threadIdx.x;
  const int db = blockIdx.x & 15;
  const int c  = (blockIdx.x >> 4) & (NC - 1);
  const int b  = blockIdx.x >> 10;
  const int d0 = db * 64;
  const size_t tokbase = (size_t)(b * S_ + c * CL);

  {
    int s = tid >> 4, jf = (tid & 15) * 4;
    size_t g = (tokbase + s) * D_ + d0 + jf;
    gload_lds16(&delta[g], &sd[s][jf]);
    gload_lds16(&x[g],     &sx[s][jf]);
    gload_lds16(&delta[g + (size_t)16 * D_], &sd[s + 16][jf]);
    gload_lds16(&x[g + (size_t)16 * D_],     &sx[s + 16][jf]);
    if (tid < 128) {
      int s2 = tid >> 2, nf = (tid & 3) * 4;
      gload_lds16(&Bm[(tokbase + s2) * N_ + nf], &sB[s2][nf]);
      gload_lds16(&Cm[(tokbase + s2) * N_ + nf], &sC[s2][nf]);
    }
  }
  const int nq = tid & 3, dl = tid >> 2;
  const int d = d0 + dl;
  float4 av = *(const float4*)&A_log[(size_t)d * N_ + nq * 4];
  float Ad0 = -__expf(av.x), Ad1 = -__expf(av.y);
  float Ad2 = -__expf(av.z), Ad3 = -__expf(av.w);
  float h0, h1, h2, h3;
  {
    size_t o = (((size_t)(b * NC + c)) * D_ + d) * N_ + nq * 4;
    float4 v = *(const float4*)&hstart[o];
    h0 = v.x; h1 = v.y; h2 = v.z; h3 = v.w;
  }
  const float Dpd = Dp[d];
  __syncthreads();

  #pragma unroll 8
  for (int s = 0; s < CL; ++s) {
    float dlt = sd[s][dl];
    float xv  = sx[s][dl];
    float dbx = dlt * xv;
    float4 Bv = *(const float4*)&sB[s][nq * 4];
    float4 Cv = *(const float4*)&sC[s][nq * 4];
    float da0 = __expf(dlt * Ad0), da1 = __expf(dlt * Ad1);
    float da2 = __expf(dlt * Ad2), da3 = __expf(dlt * Ad3);
    h0 = da0 * h0 + dbx * Bv.x;
    h1 = da1 * h1 + dbx * Bv.y;
    h2 = da2 * h2 + dbx * Bv.z;
    h3 = da3 * h3 + dbx * Bv.w;
    float y = h0 * Cv.x + h1 * Cv.y + h2 * Cv.z + h3 * Cv.w;
    y += __shfl_xor(y, 1);
    y += __shfl_xor(y, 2);
    if (nq == 0) sy[s][dl] = y + Dpd * xv;
  }
  __syncthreads();
  {
    int s = tid >> 3, j = (tid & 7) * 8;
    size_t g = (tokbase + s) * D_ + d0 + j;
    *(float4*)&ypre[g]     = *(float4*)&sy[s][j];
    *(float4*)&ypre[g + 4] = *(float4*)&sy[s][j + 4];
  }
}

// ---------------- layernorm (residual already fused) -> bf16 y ----------------
__device__ __forceinline__ float block_sum256(float v, float* sm) {
  #pragma unroll
  for (int o = 32; o > 0; o >>= 1) v += __shfl_down(v, o, 64);
  int w = threadIdx.x >> 6;
  __syncthreads();
  if ((threadIdx.x & 63) == 0) sm[w] = v;
  __syncthreads();
  return (sm[0] + sm[1]) + (sm[2] + sm[3]);
}

__global__ __launch_bounds__(256) void k_ln(
    const float* __restrict__ ypre, const float* __restrict__ g,
    const float* __restrict__ bta, unsigned short* __restrict__ ybf) {
  __shared__ float sm[4];
  const int t = blockIdx.x;
  const int tid = threadIdx.x;
  size_t base = (size_t)t * D_ + tid * 4;
  float4 v = *(const float4*)&ypre[base];
  float s1 = block_sum256(v.x + v.y + v.z + v.w, sm);
  float mu = s1 * (1.f / D_);
  float cx = v.x - mu, cy = v.y - mu, cz = v.z - mu, cw = v.w - mu;
  float s2 = block_sum256(cx*cx + cy*cy + cz*cz + cw*cw, sm);
  float rs = rsqrtf(s2 * (1.f / D_) + 1e-5f);
  float4 gg = *(const float4*)&g[tid * 4];
  float4 bb = *(const float4*)&bta[tid * 4];
  ushort4 o;
  o.x = f2b(cx * rs * gg.x + bb.x);
  o.y = f2b(cy * rs * gg.y + bb.y);
  o.z = f2b(cz * rs * gg.z + bb.z);
  o.w = f2b(cw * rs * gg.w + bb.w);
  *(ushort4*)&ybf[base] = o;
}

// ---------------- shared staging helper: 64x64 u16 tile ----------------
__device__ __forceinline__ void stage64x64(const unsigned short* __restrict__ g,
                                           size_t row0, int k0,
                                           unsigned short* lds, int tid) {
  const int r = tid >> 3, s = tid & 7;
  #pragma unroll
  for (int i = 0; i < 2; ++i) {
    const int row = i * 32 + r;
    const int gs = s ^ (row & 7);
    gload_lds16(g + ((row0 + row) << 10) + k0 + (gs << 3), lds + row * 64 + s * 8);
  }
}

// ---------------- output GEMM: O = Y x W_out^T, BM=64 BN=64, 4 blocks/CU (R10) ----------------
__global__ __launch_bounds__(256, 4) void k_out(const unsigned short* __restrict__ Y,
                                                const unsigned short* __restrict__ W,
                                                float* __restrict__ O) {
  __shared__ __align__(16) unsigned short As[2][64 * 64];  // 2x8KB
  __shared__ __align__(16) unsigned short Bs[2][64 * 64];  // 2x8KB
  const int tid = threadIdx.x;
  const int lane = tid & 63, wid = tid >> 6;
  const size_t row0 = (size_t)blockIdx.x * 64;
  const size_t col0 = (size_t)blockIdx.y * 64;
  f32x4 acc[4] = {};

  stage64x64(Y, row0, 0, As[0], tid);
  stage64x64(W, col0, 0, Bs[0], tid);
  __syncthreads();

  int cur = 0;
  const int r = lane & 15, kg = lane >> 4;
  for (int t = 0; t < 16; ++t) {
    if (t + 1 < 16) {
      stage64x64(Y, row0, (t + 1) * 64, As[cur ^ 1], tid);
      stage64x64(W, col0, (t + 1) * 64, Bs[cur ^ 1], tid);
    }
    #pragma unroll
    for (int ks = 0; ks < 2; ++ks) {
      const int arow = wid * 16 + r;
      bf16x8 a = *(const bf16x8*)&As[cur][arow * 64 + (((ks << 2) | kg) ^ (arow & 7)) * 8];
      bf16x8 b0, b1, b2, b3;
      b0 = *(const bf16x8*)&Bs[cur][(0 * 16 + r) * 64 + (((ks << 2) | kg) ^ ((0 * 16 + r) & 7)) * 8];
      b1 = *(const bf16x8*)&Bs[cur][(1 * 16 + r) * 64 + (((ks << 2) | kg) ^ ((1 * 16 + r) & 7)) * 8];
      b2 = *(const bf16x8*)&Bs[cur][(2 * 16 + r) * 64 + (((ks << 2) | kg) ^ ((2 * 16 + r) & 7)) * 8];
      b3 = *(const bf16x8*)&Bs[cur][(3 * 16 + r) * 64 + (((ks << 2) | kg) ^ ((3 * 16 + r) & 7)) * 8];
      acc[0] = __builtin_amdgcn_mfma_f32_16x16x32_bf16(a, b0, acc[0], 0, 0, 0);
      acc[1] = __builtin_amdgcn_mfma_f32_16x16x32_bf16(a, b1, acc[1], 0, 0, 0);
      acc[2] = __builtin_amdgcn_mfma_f32_16x16x32_bf16(a, b2, acc[2], 0, 0, 0);
      acc[3] = __builtin_amdgcn_mfma_f32_16x16x32_bf16(a, b3, acc[3], 0, 0, 0);
    }
    __syncthreads();
    cur ^= 1;
  }

  const int cr = lane >> 4, cc = lane & 15;
  #pragma unroll
  for (int n = 0; n < 4; ++n) {
    size_t orow = row0 + wid * 16 + cr * 4;
    float* op = O + orow * D_ + col0 + n * 16 + cc;
    #pragma unroll
    for (int j = 0; j < 4; ++j) op[(size_t)j * D_] = acc[n][j];
  }
}

extern "C" void kernel_launch(void* const* d_in, const int* in_sizes, int n_in,
                              void* d_out, int out_size, void* d_ws, size_t ws_size,
                              hipStream_t stream) {
  const float* x     = (const float*)d_in[0];
  const float* W_dtw = (const float*)d_in[1];
  const float* W_dt  = (const float*)d_in[2];
  const float* b_dt  = (const float*)d_in[3];
  const float* A_log = (const float*)d_in[4];
  const float* W_B   = (const float*)d_in[5];
  const float* W_C   = (const float*)d_in[6];
  const float* Dp    = (const float*)d_in[7];
  const float* ln_g  = (const float*)d_in[8];
  const float* ln_b  = (const float*)d_in[9];
  const float* W_out = (const float*)d_in[10];
  float* out = (float*)d_out;

  // ws_size = 256 MiB; ~72 MB used, all buffers dedicated.
  float* ws = (float*)d_ws;
  float* delta  = ws;                                   // 4,194,304 f
  float* ypre   = delta  + (size_t)BS_ * D_;            // 4,194,304 f
  float* Bm     = ypre   + (size_t)BS_ * D_;            //    65,536 f
  float* Cm     = Bm     + (size_t)BS_ * N_;            //    65,536 f
  float* hend   = Cm     + (size_t)BS_ * N_;            // 2,097,152 f
  float* hstart = hend   + (size_t)B_ * NC * D_ * N_;   // 2,097,152 f
  float* sdsum  = hstart + (size_t)B_ * NC * D_ * N_;   //   131,072 f
  float* part   = sdsum  + (size_t)B_ * NC * D_;        // 3,145,728 f
  unsigned short* Wcat = (unsigned short*)(part + (size_t)KSPLIT * BS_ * 96);
  unsigned short* wdtb = Wcat + (size_t)96 * D_;        // 65,536 u16
  unsigned short* wob  = wdtb + (size_t)D_ * R_;        // 1,048,576 u16
  unsigned short* ybf  = wob  + (size_t)D_ * D_;        // 4,194,304 u16
  unsigned short* dtb  = ybf  + (size_t)BS_ * D_;       // 262,144 u16

  k_castall<<<dim3(1184), dim3(256), 0, stream>>>(W_dtw, W_B, W_C, W_dt, W_out,
                                                  Wcat, wdtb, wob);
  k_proj<<<dim3(BS_ / 64, KSPLIT), dim3(256), 0, stream>>>(x, Wcat, part);
  k_projred<<<dim3(BS_ * 96 / 256), dim3(256), 0, stream>>>(part, dtb, Bm, Cm);
  k_delta<<<dim3(BS_ / 128, D_ / 128), dim3(256), 0, stream>>>(dtb, wdtb, b_dt, delta);
  k_scan1<<<dim3(B_ * NC * (D_ / 64)), dim3(256), 0, stream>>>(x, delta, Bm, A_log,
                                                               sdsum, hend);
  k_scan2<<<dim3(B_ * (D_ / 2)), dim3(256), 0, stream>>>(sdsum, hend, A_log, hstart);
  k_scan3<<<dim3(B_ * NC * (D_ / 64)), dim3(256), 0, stream>>>(x, delta, Bm, Cm,
                                                               A_log, hstart, Dp, ypre);
  k_ln<<<dim3(BS_), dim3(256), 0, stream>>>(ypre, ln_g, ln_b, ybf);
  k_out<<<dim3(BS_ / 64, D_ / 64), dim3(256), 0, stream>>>(ybf, wob, out);
}